// Round 9
// baseline (158.749 us; speedup 1.0000x reference)
//
#include <hip/hip_runtime.h>

typedef __bf16   bf16x8 __attribute__((ext_vector_type(8)));
typedef float    f32x4  __attribute__((ext_vector_type(4)));
typedef float    f32x2  __attribute__((ext_vector_type(2)));
typedef uint32_t u32x4  __attribute__((ext_vector_type(4)));

constexpr int N_ = 16384;
constexpr int D_ = 16;
constexpr int P_ = 8;
constexpr int H_ = 128;
constexpr int M_ = 50;

// prologue-only pack (round-half-up; matches all passing rounds)
__device__ __forceinline__ uint32_t pk_bf16(float a, float b) {
    uint32_t ua = __builtin_bit_cast(uint32_t, a) + 0x8000u;
    uint32_t ub = __builtin_bit_cast(uint32_t, b) + 0x8000u;
    return __builtin_amdgcn_perm(ub, ua, 0x07060302u);   // low=a, high=b
}
// in-loop pack: single-instruction packed convert (RNE; validated R7/R8/R11)
__device__ __forceinline__ uint32_t cvtpk(float a, float b) {
    uint32_t r;
    asm("v_cvt_pk_bf16_f32 %0, %1, %2" : "=v"(r) : "v"(a), "v"(b));
    return r;
}
__device__ __forceinline__ uint32_t cvtpk_relu(float a, float b) {
    return cvtpk(fmaxf(a, 0.0f), fmaxf(b, 0.0f));
}

// volatile 16B LDS read: cannot be promoted/hoisted across iterations (the
// R7/R9 spill cause), still gets compiler-inserted lgkmcnt (no rule-#18
// hazard, unlike inline-asm ds_read)
__device__ __forceinline__ bf16x8 lds_ldv(const bf16x8* p) {
    u32x4 v = *(volatile const u32x4*)p;
    return __builtin_bit_cast(bf16x8, v);
}

// R12: W2 STREAMED FROM LDS with one-ct-ahead register prefetch + time-split
// 2 waves/SIMD. Evidence chain: R8/R10/R11 prove an MFMA blocks its wave
// ~60 cyc regardless of independence (per-step pipe-busy invariant at ~645
// cyc while wall is 2690) -> single-wave floor = 44x60 ~= 2640 cyc/step; only
// a second resident wave can issue during the block. Prior 2-wave failures
// are each explained: barriers (R4/R6), spill + chain-head LDS latency +
// anti-hoist asm serialization (R7/R9). This design removes all three:
//  - W2 (the 128-reg hog) lives in LDS (32 KB/block, staged once); its frags
//    are prefetched one ct-group ahead, so ds_read latency hides under the
//    current ct's 4 MFMA wave-blocks (~240 cyc cover) — OFF the serial chain.
//  - w1/w3/b2/b3 register-resident (60 regs). Total ~170 regs: fits
//    2 waves/SIMD with real slack. GATE: WRITE_SIZE ~1.1 MB, VGPR <= ~210.
//  - time-split (wave h owns steps 25h..25h+24; bit-exact X replay), zero
//    in-loop barriers; one __syncthreads after staging + one at the end.
__global__ __launch_bounds__(128, 2)
void sde_fused(const float* __restrict__ X0,
               const float* __restrict__ V0,
               const float* __restrict__ Yobs,
               const float* __restrict__ noise,
               const float* __restrict__ W1, const float* __restrict__ b1,
               const float* __restrict__ W2, const float* __restrict__ b2,
               const float* __restrict__ W3, const float* __restrict__ b3,
               float* __restrict__ out)
{
    const int tid  = threadIdx.x;
    const int lane = tid & 63;
    const int half = tid >> 6;           // 0: steps 0..24, 1: steps 25..49
    const int n    = lane & 15;
    const int q    = lane >> 4;
    const int gr   = blockIdx.x * 16 + n;

    const float dt   = 0.02f;
    const float sqdt = 0.1414213562373095f;

    __shared__ bf16x8 w2lds[8][4][64];   // 32 KB: per-lane A-frags of W2
    __shared__ float  vpart[16];

    // ---- stage W2 fragments to LDS (each wave stages its 4 ct tiles) ----
#pragma unroll
    for (int cc = 0; cc < 4; ++cc) {
        const int ct = half * 4 + cc;
#pragma unroll
        for (int kt = 0; kt < 4; ++kt) {
            u32x4 u;
#pragma unroll
            for (int w = 0; w < 4; ++w) {
                int h0 = (kt * 2 + (w >> 1)) * 16 + q * 4 + (w & 1) * 2;
                u[w] = pk_bf16(W2[h0 * H_ + ct * 16 + n],
                               W2[(h0 + 1) * H_ + ct * 16 + n]);
            }
            w2lds[ct][kt][lane] = __builtin_bit_cast(bf16x8, u);
        }
    }

    // ---- register-resident small operands (both waves) ----
    bf16x8 w1f[8];
#pragma unroll
    for (int ct = 0; ct < 8; ++ct) {
        u32x4 u;
        u[0] = pk_bf16(W1[(1 + q * 4 + 0) * H_ + ct * 16 + n],
                       W1[(1 + q * 4 + 1) * H_ + ct * 16 + n]);
        u[1] = pk_bf16(W1[(1 + q * 4 + 2) * H_ + ct * 16 + n],
                       W1[(1 + q * 4 + 3) * H_ + ct * 16 + n]);
        u[2] = pk_bf16(W1[(17 + q * 2 + 0) * H_ + ct * 16 + n],
                       W1[(17 + q * 2 + 1) * H_ + ct * 16 + n]);
        u[3] = (q == 0) ? pk_bf16(b1[ct * 16 + n], W1[ct * 16 + n]) : 0u;
        w1f[ct] = __builtin_bit_cast(bf16x8, u);
    }
    bf16x8 w3f[4];
#pragma unroll
    for (int kt = 0; kt < 4; ++kt) {
        u32x4 u;
#pragma unroll
        for (int w = 0; w < 4; ++w) {
            int h0 = (kt * 2 + (w >> 1)) * 16 + q * 4 + (w & 1) * 2;
            u[w] = pk_bf16(W3[h0 * D_ + n], W3[(h0 + 1) * D_ + n]);
        }
        w3f[kt] = __builtin_bit_cast(bf16x8, u);
    }
    f32x4 b2r[8];
#pragma unroll
    for (int ct = 0; ct < 8; ++ct)
#pragma unroll
        for (int r = 0; r < 4; ++r) b2r[ct][r] = b2[ct * 16 + q * 4 + r];
    f32x4 b3r;
#pragma unroll
    for (int r = 0; r < 4; ++r) b3r[r] = b3[q * 4 + r];

    __syncthreads();   // W2 staged

    // ---- state ----
    f32x4 x = *(const f32x4*)&X0[gr * D_ + q * 4];
    f32x2 y2 = *(const f32x2*)&Yobs[gr * P_ + q * 2];
    const uint32_t yw = pk_bf16(y2[0], y2[1]);
    const float* npb = noise + (size_t)gr * D_ + q * 4;

    // ---- wave 1: bit-exact replay of the X recurrence through steps 0..24 ----
    if (half == 1) {
#pragma unroll 2
        for (int m = 0; m < 25; ++m) {
            f32x4 e = *(const f32x4*)(npb + (size_t)m * N_ * D_);
#pragma unroll
            for (int r = 0; r < 4; ++r)
                x[r] = fmaf(x[r], 0.98f, sqdt * e[r]);
        }
    }

    const int s0 = half * 25;
    float t = half ? 0.5f : 0.0f;        // 25*dt == 0.5 (verified handoff)
    f32x4 e0 = *(const f32x4*)(npb + (size_t)s0 * N_ * D_);
    float vacc = 0.0f;

#pragma unroll 1
    for (int i = 0; i < 25; ++i) {
        const int m  = s0 + i;
        const int mn = (m + 1 < M_) ? (m + 1) : (M_ - 1);
        f32x4 e1 = *(const f32x4*)(npb + (size_t)mn * N_ * D_);

        // ---- layer 1 B fragment: [X(4) | Y(2) | one | t] ----
        u32x4 au;
        au[0] = cvtpk(x[0], x[1]);
        au[1] = cvtpk(x[2], x[3]);
        au[2] = yw;
        au[3] = (q == 0) ? cvtpk(1.0f, t) : 0u;
        bf16x8 a0 = __builtin_bit_cast(bf16x8, au);

        // ---- layer 1: 8 MFMAs (R0 form) ----
        f32x4 h1c[8];
#pragma unroll
        for (int ct = 0; ct < 8; ++ct)
            h1c[ct] = __builtin_amdgcn_mfma_f32_16x16x32_bf16(
                w1f[ct], a0, (f32x4){0.f, 0.f, 0.f, 0.f}, 0, 0, 0);

        bf16x8 h1b[4];
#pragma unroll
        for (int kt = 0; kt < 4; ++kt) {
            u32x4 u;
            u[0] = cvtpk_relu(h1c[2 * kt][0], h1c[2 * kt][1]);
            u[1] = cvtpk_relu(h1c[2 * kt][2], h1c[2 * kt][3]);
            u[2] = cvtpk_relu(h1c[2 * kt + 1][0], h1c[2 * kt + 1][1]);
            u[3] = cvtpk_relu(h1c[2 * kt + 1][2], h1c[2 * kt + 1][3]);
            h1b[kt] = __builtin_bit_cast(bf16x8, u);
        }

        // ---- layer 2: W2 streamed from LDS, one ct-group prefetched ahead.
        //      w2buf[parity][kt]; after full unroll all indices are static.
        bf16x8 w2buf[2][4];
#pragma unroll
        for (int kt = 0; kt < 4; ++kt) w2buf[0][kt] = lds_ldv(&w2lds[0][kt][lane]);

        f32x4 hprev;                 // even-ct accumulator awaiting its pair
        bf16x8 h2b[4];
#pragma unroll
        for (int ct = 0; ct < 8; ++ct) {
            if (ct < 7) {
#pragma unroll
                for (int kt = 0; kt < 4; ++kt)
                    w2buf[(ct + 1) & 1][kt] = lds_ldv(&w2lds[ct + 1][kt][lane]);
            }
            f32x4 c = b2r[ct];
#pragma unroll
            for (int kt = 0; kt < 4; ++kt)
                c = __builtin_amdgcn_mfma_f32_16x16x32_bf16(
                    w2buf[ct & 1][kt], h1b[kt], c, 0, 0, 0);
            if ((ct & 1) == 0) {
                hprev = c;
            } else {
                u32x4 u;
                u[0] = cvtpk_relu(hprev[0], hprev[1]);
                u[1] = cvtpk_relu(hprev[2], hprev[3]);
                u[2] = cvtpk_relu(c[0], c[1]);
                u[3] = cvtpk_relu(c[2], c[3]);
                h2b[ct >> 1] = __builtin_bit_cast(bf16x8, u);
            }
        }

        // ---- layer 3: two 2-chains (R0 form) ----
        f32x4 za = __builtin_amdgcn_mfma_f32_16x16x32_bf16(w3f[0], h2b[0], b3r, 0, 0, 0);
        za = __builtin_amdgcn_mfma_f32_16x16x32_bf16(w3f[1], h2b[1], za, 0, 0, 0);
        f32x4 zb = __builtin_amdgcn_mfma_f32_16x16x32_bf16(
            w3f[2], h2b[2], (f32x4){0.f, 0.f, 0.f, 0.f}, 0, 0, 0);
        zb = __builtin_amdgcn_mfma_f32_16x16x32_bf16(w3f[3], h2b[3], zb, 0, 0, 0);

        // ---- V partial + X update ----
#pragma unroll
        for (int r = 0; r < 4; ++r) {
            float z  = za[r] + zb[r];
            float wn = sqdt * e0[r];
            vacc = fmaf(z, wn, fmaf(0.01f * z, z, vacc));   // z*wn + dt/2*z^2
            x[r] = fmaf(x[r], 0.98f, wn);                   // (1-dt)*x + wn
        }

        e0 = e1;
        t += dt;
    }

    // ---- V reduction across the 4 q-groups within each wave ----
    float part = vacc;
    part += __shfl_xor(part, 16);
    part += __shfl_xor(part, 32);

    // ---- combine the two time-halves ----
    if (half == 0 && q == 0) vpart[n] = part;
    __syncthreads();
    if (half == 1) {
        *(f32x4*)&out[gr * D_ + q * 4] = x;                 // final X (step 50)
        if (q == 0) out[N_ * D_ + gr] = V0[gr] + vpart[n] + part;
    }
}

extern "C" void kernel_launch(void* const* d_in, const int* in_sizes, int n_in,
                              void* d_out, int out_size, void* d_ws, size_t ws_size,
                              hipStream_t stream)
{
    const float* X0 = (const float*)d_in[0];
    const float* V0 = (const float*)d_in[1];
    const float* Y  = (const float*)d_in[2];
    const float* nz = (const float*)d_in[3];
    const float* W1 = (const float*)d_in[4];
    const float* b1 = (const float*)d_in[5];
    const float* W2 = (const float*)d_in[6];
    const float* b2 = (const float*)d_in[7];
    const float* W3 = (const float*)d_in[8];
    const float* b3 = (const float*)d_in[9];
    float* out = (float*)d_out;

    sde_fused<<<N_ / 16, 128, 0, stream>>>(X0, V0, Y, nz, W1, b1, W2, b2, W3, b3, out);
}